// Round 5
// baseline (65.064 us; speedup 1.0000x reference)
//
#include <hip/hip_runtime.h>
#include <stdint.h>

#define TPB 256
#define CHUNK_ROWS 128
#define ROW_F 25
#define CHUNK_FA (CHUNK_ROWS * ROW_F)      // 3200 floats per array per chunk
#define CHUNK_F4A (CHUNK_FA / 4)           // 800 float4 per array
#define CHUNK_F4  (2 * CHUNK_F4A)          // 1600 float4 both arrays
#define BUF_FLOATS (2 * CHUNK_FA)          // 6400 floats = 25.6 KB per buffer
#define NISSUE 7                           // ceil(1600 f4 / 256 threads)

typedef __attribute__((address_space(3))) uint32_t lds_u32;
typedef const __attribute__((address_space(1))) uint32_t glob_u32;

// Slim judge: ranks of out == ranks of pre (softmax monotone); "within" in
// scaled form |3*e_i - t_i*S| <= 0.09*S (no divide on the critical chain).
__device__ __forceinline__ void judge_group(const float* __restrict__ p,
                                            const float* __restrict__ t,
                                            int& calc, int& acc) {
    const float GAPv = 0.03f;   // 3 * 0.01
    float p0 = p[0], p1 = p[1], p2 = p[2], p3 = p[3];
    float t0 = t[0], t1 = t[1], t2 = t[2], t3 = t[3];

    float m  = fmaxf(fmaxf(p0, p1), fmaxf(p2, p3));
    float e0 = __expf(p0 - m), e1 = __expf(p1 - m);
    float e2 = __expf(p2 - m), e3 = __expf(p3 - m);
    float S  = (e0 + e1) + (e2 + e3);
    float thr = 0.09f * S;
    float w0 = fmaf(3.0f, e0, -t0 * S);
    float w1 = fmaf(3.0f, e1, -t1 * S);
    float w2 = fmaf(3.0f, e2, -t2 * S);
    float w3 = fmaf(3.0f, e3, -t3 * S);
    bool within = fabsf(w0) <= thr && fabsf(w1) <= thr &&
                  fabsf(w2) <= thr && fabsf(w3) <= thr;

    // stable ranks of p (== ranks of out). g_ij = (p_j < p_i), i<j.
    int g01 = p1 < p0, g02 = p2 < p0, g03 = p3 < p0;
    int g12 = p2 < p1, g13 = p3 < p1, g23 = p3 < p2;
    int ro0 = g01 + g02 + g03;
    int ro1 = 1 - g01 + g12 + g13;
    int ro2 = 2 - g02 - g12 + g23;
    int ro3 = 3 - g03 - g13 - g23;

    int h01 = t1 < t0, h02 = t2 < t0, h03 = t3 < t0;
    int h12 = t2 < t1, h13 = t3 < t1, h23 = t3 < t2;
    int rt0 = h01 + h02 + h03;
    int rt1 = 1 - h01 + h12 + h13;
    int rt2 = 2 - h02 - h12 + h23;
    int rt3 = 3 - h03 - h13 - h23;

    // sorted target values (ascending): st0 <= st1 <= st2
    float l01 = fminf(t0, t1), x01 = fmaxf(t0, t1);
    float l23 = fminf(t2, t3), x23 = fmaxf(t2, t3);
    float st0 = fminf(l01, l23), mlo = fmaxf(l01, l23);
    float mhi = fminf(x01, x23);
    float st1 = fminf(mlo, mhi), st2 = fmaxf(mlo, mhi);
    float d1 = st1 - st0;
    float d2 = st2 - st1;

    bool jump = within && (
        ((d1 < GAPv) & (d2 < GAPv)) ||
        ((d1 < GAPv) & (ro2 == rt2)) ||
        ((d2 < GAPv) & (ro0 == rt0)));

    int nz = (t0 == 0.0f) + (t1 == 0.0f) + (t2 == 0.0f) + (t3 == 0.0f);
    bool match_all = (ro0 == rt0) & (ro1 == rt1) & (ro2 == rt2) & (ro3 == rt3);

    bool s2 = ((ro0 == 2) & (rt0 == 2)) | ((ro1 == 2) & (rt1 == 2)) |
              ((ro2 == 2) & (rt2 == 2)) | ((ro3 == 2) & (rt3 == 2));
    bool s3 = ((ro0 == 3) & (rt0 == 3)) | ((ro1 == 3) & (rt1 == 3)) |
              ((ro2 == 3) & (rt2 == 3)) | ((ro3 == 3) & (rt3 == 3));

    bool c_lt2 = !jump & (nz < 2);
    bool c_eq2 = !jump & (nz == 2) & s2 & s3;
    bool c_eq3 = !jump & (nz == 3) & (ro3 == 3);

    calc += (jump | c_lt2 | c_eq2 | c_eq3) ? 1 : 0;
    acc  += (jump | (c_lt2 & match_all) | c_eq2 | c_eq3) ? 1 : 0;
}

// Stage one 128-row chunk (pre||tar, 25600 B) into buf via global_load_lds.
// Issues k=0..5 cover f4 [k*256, (k+1)*256); k=6 covers f4 [1536,1600):
// all 4 waves mirror wave 0's addresses (same-value duplicate writes) so
// every wave issues exactly NISSUE VMEM ops (uniform vmcnt accounting).
__device__ __forceinline__ void stage_chunk(const float4* __restrict__ pre4,
                                            const float4* __restrict__ tar4,
                                            int chunk, int total4a, float* buf,
                                            int tid, int lane, int wid) {
#pragma unroll
    for (int k = 0; k < NISSUE; ++k) {
        int j       = (k < 6) ? (k * 256 + tid) : (1536 + lane);
        int ldsbyte = (k < 6) ? (k * 4096 + wid * 1024) : (6 * 4096);
        int local   = (j < CHUNK_F4A) ? j : (j - CHUNK_F4A);
        int ia      = chunk * CHUNK_F4A + local;
        if (ia >= total4a) ia = total4a - 1;            // tail clamp (rows >= B unused)
        const float4* src = (j < CHUNK_F4A) ? (pre4 + ia) : (tar4 + ia);
        __builtin_amdgcn_global_load_lds((glob_u32*)(const void*)src,
                                         (lds_u32*)(void*)((char*)buf + ldsbyte),
                                         16, 0, 0);
    }
}

__global__ __launch_bounds__(TPB)
void recall_main_kernel(const float* __restrict__ pre,
                        const float* __restrict__ tar,
                        float* __restrict__ partial,
                        unsigned int* __restrict__ counter,
                        float* __restrict__ out,
                        int B, int nchunks, int grid) {
    __shared__ __align__(16) float s_buf[2][BUF_FLOATS];   // 51.2 KB
    __shared__ float s_red[8];
    __shared__ unsigned int s_done;

    const int t    = threadIdx.x;
    const int lane = t & 63;
    const int wid  = t >> 6;
    const int total4a = (B * ROW_F) >> 2;   // float4 count per input array

    const float4* pre4 = (const float4*)pre;
    const float4* tar4 = (const float4*)tar;

    float csum = 0.0f, vsum = 0.0f;
    int cur = 0;

    // prologue: stage first chunk
    if ((int)blockIdx.x < nchunks)
        stage_chunk(pre4, tar4, blockIdx.x, total4a, s_buf[0], t, lane, wid);

    for (int c = blockIdx.x; c < nchunks; c += grid) {
        const int nc = c + grid;
        const bool has_next = nc < nchunks;

        if (has_next)
            stage_chunk(pre4, tar4, nc, total4a, s_buf[cur ^ 1], t, lane, wid);

        // wait for CURRENT chunk's 7 loads; leave next chunk's 7 in flight
        if (has_next) asm volatile("s_waitcnt vmcnt(7)" ::: "memory");
        else          asm volatile("s_waitcnt vmcnt(0)" ::: "memory");
        __builtin_amdgcn_s_barrier();          // all waves' current-chunk loads landed
        asm volatile("" ::: "memory");         // no hoisting of LDS reads above barrier

        if (t < CHUNK_ROWS) {
            int row = c * CHUNK_ROWS + t;
            if (row < B) {
                const float* rp = &s_buf[cur][t * ROW_F];
                const float* rt = &s_buf[cur][CHUNK_FA + t * ROW_F];
                int calc = 0, acc = 0;
#pragma unroll
                for (int g = 0; g < 6; ++g)
                    judge_group(rp + g * 4, rt + g * 4, calc, acc);
                if (calc > 0) {
                    csum += __fdividef((float)acc, (float)calc);
                    vsum += 1.0f;
                }
            }
        }

        asm volatile("" ::: "memory");
        __builtin_amdgcn_s_barrier();          // everyone done reading buf[cur]
        cur ^= 1;
    }

    // block reduction (deterministic)
#pragma unroll
    for (int off = 32; off > 0; off >>= 1) {
        csum += __shfl_down(csum, off);
        vsum += __shfl_down(vsum, off);
    }
    if (lane == 0) { s_red[wid] = csum; s_red[4 + wid] = vsum; }
    __syncthreads();
    if (t == 0) {
        partial[2 * blockIdx.x]     = s_red[0] + s_red[1] + s_red[2] + s_red[3];
        partial[2 * blockIdx.x + 1] = s_red[4] + s_red[5] + s_red[6] + s_red[7];
        __threadfence();                        // publish partials (device scope)
        s_done = atomicAdd(counter, 1u);
    }
    __syncthreads();

    // last finished block folds all partials (fixed order -> deterministic)
    if (s_done == (unsigned int)grid - 1u) {
        __threadfence();                        // acquire all blocks' partials
        float c = 0.0f, v = 0.0f;
        for (int i = t; i < grid; i += TPB) {
            c += partial[2 * i];
            v += partial[2 * i + 1];
        }
#pragma unroll
        for (int off = 32; off > 0; off >>= 1) {
            c += __shfl_down(c, off);
            v += __shfl_down(v, off);
        }
        if (lane == 0) { s_red[wid] = c; s_red[4 + wid] = v; }
        __syncthreads();
        if (t == 0) {
            float cs = s_red[0] + s_red[1] + s_red[2] + s_red[3];
            float vs = s_red[4] + s_red[5] + s_red[6] + s_red[7];
            out[0] = (vs > 0.0f) ? (cs / vs) : 0.0f;
        }
    }
}

extern "C" void kernel_launch(void* const* d_in, const int* in_sizes, int n_in,
                              void* d_out, int out_size, void* d_ws, size_t ws_size,
                              hipStream_t stream) {
    const float* pre = (const float*)d_in[0];
    const float* tar = (const float*)d_in[1];
    float* out = (float*)d_out;
    float* partial = (float*)d_ws;
    unsigned int* counter = (unsigned int*)((char*)d_ws + 16384);

    int B = in_sizes[0] / ROW_F;
    int nchunks = (B + CHUNK_ROWS - 1) / CHUNK_ROWS;

    // 3 blocks/CU (51.2 KB LDS each) x 256 CU = 768 blocks, exactly resident
    int grid = 768;
    if (grid > nchunks) grid = nchunks;
    if (grid < 1) grid = 1;

    hipMemsetAsync(counter, 0, sizeof(unsigned int), stream);
    recall_main_kernel<<<grid, TPB, 0, stream>>>(pre, tar, partial, counter, out,
                                                 B, nchunks, grid);
}